// Round 3
// baseline (104.303 us; speedup 1.0000x reference)
//
#include <hip/hip_runtime.h>

// QuerySpecificClusterModel: B=256 samples, n=64 points, d=768.
// Round 3: fix the round-2 regression root cause — compiler chose 128 VGPRs
// (targeting unusable occupancy) and spilled ~100 regs/thread to scratch
// (50 MB WRITE_SIZE/dispatch). __launch_bounds__(512, 2) raises the VGPR
// budget to 256 (2 waves/EU == our actual 1-block/CU residency) -> no spill.
// Everything else identical to round 2 (DPP argmin, ballot masks, swizzled
// 8-wave Gram).

#define NPTS 64
#define DIM 768
#define CH 128
#define NCH 6
#define NT 512
#define NW 8
#define BIGF 1e9f

// ---- DPP lexicographic argmin over 64 lanes: (val, flatidx), lowest idx tie ----
template <int CTRL>
__device__ __forceinline__ void amin_step(float& vf, int& fi) {
  int sv = __builtin_amdgcn_update_dpp(__float_as_int(vf), __float_as_int(vf),
                                       CTRL, 0xF, 0xF, false);
  int si = __builtin_amdgcn_update_dpp(fi, fi, CTRL, 0xF, 0xF, false);
  float svf = __int_as_float(sv);
  bool take = (svf < vf) || (svf == vf && si < fi);
  vf = take ? svf : vf;
  fi = take ? si : fi;
}

__device__ __forceinline__ void argmin64(float& vf, int& fi) {
  amin_step<0x121>(vf, fi);   // row_ror:1
  amin_step<0x122>(vf, fi);   // row_ror:2
  amin_step<0x124>(vf, fi);   // row_ror:4
  amin_step<0x128>(vf, fi);   // row_ror:8
  amin_step<0x142>(vf, fi);   // row_bcast:15
  amin_step<0x143>(vf, fi);   // row_bcast:31
  vf = __int_as_float(__builtin_amdgcn_readlane(__float_as_int(vf), 63));
  fi = __builtin_amdgcn_readlane(fi, 63);
}

__global__ __launch_bounds__(NT, 2) void fused_kernel(
    const float* __restrict__ q,      // [256,768]
    const float* __restrict__ psg,    // [256,64,768]
    const int*   __restrict__ labels, // [256,64]
    float* __restrict__ simS_o, float* __restrict__ disS_o,
    int* __restrict__ simC_o, int* __restrict__ errC_o)
{
  __shared__ __align__(16) float s[NPTS][132];   // staged scaled chunk (swizzled)
  __shared__ __align__(16) float Dw[NPTS][65];   // distance matrix
  __shared__ float diag[NPTS];
  __shared__ __align__(16) int cls[NPTS];

  const int b = blockIdx.x;
  const int t = threadIdx.x;
  const int w = t >> 6;          // wave id 0..7
  const int lane = t & 63;
  const int g = lane >> 3;
  const int h = lane & 7;
  const int i0 = g << 3;
  const int j0 = h << 3;

  const float* qb = q + (size_t)b * DIM;
  const float* pb = psg + (size_t)b * NPTS * DIM;

  float acc[8][8] = {};

  const int kvq = t & 31;        // float4 col within chunk (staging)
  const int irb = t >> 5;        // staging row base 0..15

  // prefetch chunk 0
  float4 qv, pv[4];
  qv = *reinterpret_cast<const float4*>(qb + (kvq << 2));
  #pragma unroll
  for (int r = 0; r < 4; ++r)
    pv[r] = *reinterpret_cast<const float4*>(pb + (size_t)(irb + (r << 4)) * DIM + (kvq << 2));

  for (int c = 0; c < NCH; ++c) {
    // write staged (scaled) chunk c; swizzle (i>>3) is distinct per g-group
    #pragma unroll
    for (int r = 0; r < 4; ++r) {
      int i = irb + (r << 4);
      float4 sv;
      sv.x = pv[r].x * qv.x; sv.y = pv[r].y * qv.y;
      sv.z = pv[r].z * qv.z; sv.w = pv[r].w * qv.w;
      *reinterpret_cast<float4*>(&s[i][(kvq ^ (i >> 3)) << 2]) = sv;
    }
    __syncthreads();
    // prefetch chunk c+1 (latency hides under compute below)
    if (c + 1 < NCH) {
      qv = *reinterpret_cast<const float4*>(qb + (c + 1) * CH + (kvq << 2));
      #pragma unroll
      for (int r = 0; r < 4; ++r)
        pv[r] = *reinterpret_cast<const float4*>(
            pb + (size_t)(irb + (r << 4)) * DIM + (c + 1) * CH + (kvq << 2));
    }
    // K split across 8 waves: wave w owns k4 = w*4 .. w*4+3
    #pragma unroll
    for (int kk = 0; kk < 4; ++kk) {
      int k4 = (w << 2) + kk;
      float4 a4[8];
      #pragma unroll
      for (int ii = 0; ii < 8; ++ii) {
        int row = i0 + ii;
        a4[ii] = *reinterpret_cast<const float4*>(&s[row][(k4 ^ (row >> 3)) << 2]);
      }
      #pragma unroll
      for (int jj = 0; jj < 8; ++jj) {
        int row = j0 + jj;
        float4 b4 = *reinterpret_cast<const float4*>(&s[row][(k4 ^ (row >> 3)) << 2]);
        #pragma unroll
        for (int ii = 0; ii < 8; ++ii) {
          acc[ii][jj] += a4[ii].x * b4.x;
          acc[ii][jj] += a4[ii].y * b4.y;
          acc[ii][jj] += a4[ii].z * b4.z;
          acc[ii][jj] += a4[ii].w * b4.w;
        }
      }
    }
    __syncthreads();
  }

  // Cross-wave reduction into wave 0 (fixed order src 1..7; XOR-swizzled slots)
  float* fs = &s[0][0];
  #pragma unroll 1
  for (int src = 1; src < NW; ++src) {
    if (w == src) {
      #pragma unroll
      for (int ii = 0; ii < 8; ++ii) {
        #pragma unroll
        for (int jq = 0; jq < 2; ++jq) {
          int slot = ii * 2 + jq;
          float4 vv = make_float4(acc[ii][jq * 4 + 0], acc[ii][jq * 4 + 1],
                                  acc[ii][jq * 4 + 2], acc[ii][jq * 4 + 3]);
          *reinterpret_cast<float4*>(&fs[(lane << 6) + ((slot ^ (lane & 7)) << 2)]) = vv;
        }
      }
    }
    __syncthreads();
    if (w == 0) {
      #pragma unroll
      for (int ii = 0; ii < 8; ++ii) {
        #pragma unroll
        for (int jq = 0; jq < 2; ++jq) {
          int slot = ii * 2 + jq;
          float4 vv = *reinterpret_cast<const float4*>(
              &fs[(lane << 6) + ((slot ^ (lane & 7)) << 2)]);
          acc[ii][jq * 4 + 0] += vv.x; acc[ii][jq * 4 + 1] += vv.y;
          acc[ii][jq * 4 + 2] += vv.z; acc[ii][jq * 4 + 3] += vv.w;
        }
      }
    }
    __syncthreads();
  }

  if (w != 0) return;            // wave 0 continues alone; same-wave LDS is in-order

  // diag (squared norms) then distances (diag exactly 0)
  if (g == h) {
    #pragma unroll
    for (int ii = 0; ii < 8; ++ii) diag[i0 + ii] = acc[ii][ii];
  }
  #pragma unroll
  for (int ii = 0; ii < 8; ++ii) {
    float di = diag[i0 + ii];
    #pragma unroll
    for (int jj = 0; jj < 8; ++jj) {
      float d2 = di + diag[j0 + jj] - 2.f * acc[ii][jj];
      d2 = fmaxf(d2, 0.f);
      Dw[i0 + ii][j0 + jj] = (d2 > 0.f) ? sqrtf(d2) : 0.f;
    }
  }

  // ---------------- clustering (single wave, lane l owns row l) -------------
  const int l = lane;
  float* Dm = &Dw[0][0];
  int tl = labels[b * NPTS + l];

  // label-equality mask + unique-label count via 8 ballots
  unsigned long long sMask = 0ull;
  int kcnt = 0;
  #pragma unroll
  for (int v = 0; v < 8; ++v) {
    unsigned long long mv = __ballot(tl == v);
    kcnt += (mv != 0ull) ? 1 : 0;
    if (tl == v) sMask = mv;
  }
  int simC = __popcll(sMask);

  // own-row scan: sim/dis sums + row min (strict <: lowest j wins ties)
  float simS = 0.f, disS = 0.f;
  float mval = BIGF; int midx = 0;
  const float* rowp = Dm + l * 65;
  #pragma unroll
  for (int j = 0; j < NPTS; ++j) {
    float v = rowp[j];
    bool sim = (sMask >> j) & 1ull;
    simS += sim ? v : 0.f;
    disS += sim ? 0.f : v;
    bool better = (j != l) && (v < mval);
    mval = better ? v : mval;
    midx = better ? j : midx;
  }
  Dm[l * 65 + l] = BIGF;         // reference inits diagonal to BIG

  unsigned long long actm = ~0ull;
  int cl = l;
  const int merges = NPTS - kcnt;
  #pragma unroll 1
  for (int m = 0; m < merges; ++m) {
    // global argmin over rows' (minval, flat=l*64+midx), lowest-flat tie-break
    bool act = (actm >> l) & 1ull;
    float vf = act ? mval : BIGF;
    int fi = (l << 6) | midx;
    argmin64(vf, fi);            // uniform result in all lanes
    const int a = fi >> 6;       // a < bb by symmetry + lowest-flat
    const int bb = fi & 63;

    // newrow[l] = min(D[l][a], D[l][bb]); update col a and row a
    float va = Dm[l * 65 + a];
    float vb = Dm[l * 65 + bb];
    float nr = fminf(va, vb);
    Dm[l * 65 + a] = nr;
    Dm[a * 65 + l] = nr;

    actm &= ~(1ull << bb);
    cl = (cl == bb) ? a : cl;

    // per-row min maintenance (nr >= mval always; col bb removed, col a -> nr)
    bool actrow = ((actm >> l) & 1ull) && (l != a);
    if (actrow) {
      if (midx == bb) midx = a;
      else if (nr == mval && a < midx) midx = a;
    }
    // fresh rescan for row a: candidates are nr across active lanes != a
    float cv = actrow ? nr : BIGF;
    int cj = l;
    argmin64(cv, cj);
    if (l == a) { mval = cv; midx = cj; }
  }

  // err count via masks: ec = popcount(clusterMask XOR labelMask)
  cls[l] = cl;
  unsigned long long cMask = 0ull;
  const int4* cp = reinterpret_cast<const int4*>(cls);
  #pragma unroll
  for (int jq = 0; jq < 16; ++jq) {
    int4 c4 = cp[jq];
    cMask |= ((unsigned long long)(c4.x == cl)) << (jq * 4 + 0);
    cMask |= ((unsigned long long)(c4.y == cl)) << (jq * 4 + 1);
    cMask |= ((unsigned long long)(c4.z == cl)) << (jq * 4 + 2);
    cMask |= ((unsigned long long)(c4.w == cl)) << (jq * 4 + 3);
  }
  int ec = __popcll(cMask ^ sMask);

  // wave reductions (deterministic butterfly; one-time)
  #pragma unroll
  for (int off = 32; off; off >>= 1) {
    simS += __shfl_xor(simS, off);
    disS += __shfl_xor(disS, off);
    simC += __shfl_xor(simC, off);
    ec   += __shfl_xor(ec, off);
  }
  if (l == 0) {
    simS_o[b] = simS; disS_o[b] = disS;
    simC_o[b] = simC; errC_o[b] = ec;
  }
}

__global__ __launch_bounds__(64) void finalize_kernel(
    const float* __restrict__ simS, const float* __restrict__ disS,
    const int* __restrict__ simC, const int* __restrict__ errC,
    float* __restrict__ out)
{
  const int l = threadIdx.x;
  double ss = 0.0, dd = 0.0, sc = 0.0, ec = 0.0;
  #pragma unroll
  for (int r = 0; r < 4; ++r) {
    int i = (r << 6) + l;        // fixed order -> deterministic
    ss += (double)simS[i];
    dd += (double)disS[i];
    sc += (double)simC[i];
    ec += (double)errC[i];
  }
  #pragma unroll
  for (int off = 32; off; off >>= 1) {
    ss += __shfl_xor(ss, off);
    dd += __shfl_xor(dd, off);
    sc += __shfl_xor(sc, off);
    ec += __shfl_xor(ec, off);
  }
  if (l == 0) {
    const double total = 256.0 * 4096.0;
    double ms = ss / sc;
    double md = dd / (total - sc);
    out[0] = (float)(ec / 256.0 + 0.5 * (ms - md));
  }
}

extern "C" void kernel_launch(void* const* d_in, const int* in_sizes, int n_in,
                              void* d_out, int out_size, void* d_ws, size_t ws_size,
                              hipStream_t stream) {
  const float* q      = (const float*)d_in[0];
  const float* psg    = (const float*)d_in[1];
  const int*   labels = (const int*)d_in[2];
  float* out = (float*)d_out;

  float* simS = (float*)d_ws;          // [256]
  float* disS = simS + 256;            // [256]
  int*   simC = (int*)(disS + 256);    // [256]
  int*   errC = simC + 256;            // [256]

  fused_kernel<<<256, NT, 0, stream>>>(q, psg, labels, simS, disS, simC, errC);
  finalize_kernel<<<1, 64, 0, stream>>>(simS, disS, simC, errC, out);
}

// Round 4
// 100.150 us; speedup vs baseline: 1.0415x; 1.0415x over previous
//
#include <hip/hip_runtime.h>

// QuerySpecificClusterModel: B=256 samples, n=64 points, d=768.
// Round 4: kill the spill by shrinking the register working set (no long-lived
// prefetch regs; round-1-style load->scale->store staging) instead of fighting
// the 128-VGPR cap, and replace the serialized 7-step cross-wave reduce
// (14 barriers) with a 3-step tree reduce through LDS P[4][64][64]
// (XOR slot-swizzle, <=4-way conflicts). DPP argmin tail unchanged.

#define NPTS 64
#define DIM 768
#define CH 128
#define NCH 6
#define NT 512
#define BIGF 1e9f

// ---- DPP lexicographic argmin over 64 lanes: (val, flatidx), lowest idx tie ----
template <int CTRL>
__device__ __forceinline__ void amin_step(float& vf, int& fi) {
  int sv = __builtin_amdgcn_update_dpp(__float_as_int(vf), __float_as_int(vf),
                                       CTRL, 0xF, 0xF, false);
  int si = __builtin_amdgcn_update_dpp(fi, fi, CTRL, 0xF, 0xF, false);
  float svf = __int_as_float(sv);
  bool take = (svf < vf) || (svf == vf && si < fi);
  vf = take ? svf : vf;
  fi = take ? si : fi;
}

__device__ __forceinline__ void argmin64(float& vf, int& fi) {
  amin_step<0x121>(vf, fi);   // row_ror:1
  amin_step<0x122>(vf, fi);   // row_ror:2
  amin_step<0x124>(vf, fi);   // row_ror:4
  amin_step<0x128>(vf, fi);   // row_ror:8
  amin_step<0x142>(vf, fi);   // row_bcast:15
  amin_step<0x143>(vf, fi);   // row_bcast:31
  vf = __int_as_float(__builtin_amdgcn_readlane(__float_as_int(vf), 63));
  fi = __builtin_amdgcn_readlane(fi, 63);
}

// ---- tree-reduce partial helpers (XOR slot-swizzle: <=4-way conflicts) ----
__device__ __forceinline__ void wr_partial(float* __restrict__ Pb,
                                           const float (&acc)[8][8], int g, int h) {
  #pragma unroll
  for (int ii = 0; ii < 8; ++ii) {
    const int row = (g << 3) + ii;
    #pragma unroll
    for (int jq = 0; jq < 2; ++jq) {
      const int sl = ((h << 1) + jq) ^ g;
      float4 v = make_float4(acc[ii][jq * 4 + 0], acc[ii][jq * 4 + 1],
                             acc[ii][jq * 4 + 2], acc[ii][jq * 4 + 3]);
      *reinterpret_cast<float4*>(Pb + (row << 6) + (sl << 2)) = v;
    }
  }
}

__device__ __forceinline__ void rd_accum(const float* __restrict__ Pb,
                                         float (&acc)[8][8], int g, int h) {
  #pragma unroll
  for (int ii = 0; ii < 8; ++ii) {
    const int row = (g << 3) + ii;
    #pragma unroll
    for (int jq = 0; jq < 2; ++jq) {
      const int sl = ((h << 1) + jq) ^ g;
      float4 v = *reinterpret_cast<const float4*>(Pb + (row << 6) + (sl << 2));
      acc[ii][jq * 4 + 0] += v.x; acc[ii][jq * 4 + 1] += v.y;
      acc[ii][jq * 4 + 2] += v.z; acc[ii][jq * 4 + 3] += v.w;
    }
  }
}

__global__ __launch_bounds__(NT) void fused_kernel(
    const float* __restrict__ q,      // [256,768]
    const float* __restrict__ psg,    // [256,64,768]
    const int*   __restrict__ labels, // [256,64]
    float* __restrict__ simS_o, float* __restrict__ disS_o,
    int* __restrict__ simC_o, int* __restrict__ errC_o)
{
  __shared__ __align__(16) float s[NPTS][132];        // staged scaled chunk (swizzled)
  __shared__ __align__(16) float P[4][NPTS][NPTS];    // tree-reduce scratch (64KB)
  __shared__ __align__(16) float Dw[NPTS][65];        // distance matrix
  __shared__ float diag[NPTS];
  __shared__ __align__(16) int cls[NPTS];

  const int b = blockIdx.x;
  const int t = threadIdx.x;
  const int w = t >> 6;          // wave id 0..7
  const int lane = t & 63;
  const int g = lane >> 3;
  const int h = lane & 7;
  const int i0 = g << 3;
  const int j0 = h << 3;

  const float* qb = q + (size_t)b * DIM;
  const float* pb = psg + (size_t)b * NPTS * DIM;

  float acc[8][8] = {};

  const int kvq = t & 31;        // float4 col within chunk (staging)
  const int irb = t >> 5;        // staging row base 0..15

  for (int c = 0; c < NCH; ++c) {
    // stage scaled chunk c (short-lived regs only; compiler batches the loads)
    float4 qv = *reinterpret_cast<const float4*>(qb + c * CH + (kvq << 2));
    #pragma unroll
    for (int r = 0; r < 4; ++r) {
      const int i = irb + (r << 4);
      float4 pv = *reinterpret_cast<const float4*>(
          pb + (size_t)i * DIM + c * CH + (kvq << 2));
      float4 sv = make_float4(pv.x * qv.x, pv.y * qv.y, pv.z * qv.z, pv.w * qv.w);
      *reinterpret_cast<float4*>(&s[i][(kvq ^ (i >> 3)) << 2]) = sv;
    }
    __syncthreads();
    // K split across 8 waves: wave w owns k4 = w*4 .. w*4+3
    #pragma unroll
    for (int kk = 0; kk < 4; ++kk) {
      const int k4 = (w << 2) + kk;
      float4 a4[8];
      #pragma unroll
      for (int ii = 0; ii < 8; ++ii) {
        const int row = i0 + ii;
        a4[ii] = *reinterpret_cast<const float4*>(&s[row][(k4 ^ (row >> 3)) << 2]);
      }
      #pragma unroll
      for (int jj = 0; jj < 8; ++jj) {
        const int row = j0 + jj;
        float4 b4 = *reinterpret_cast<const float4*>(&s[row][(k4 ^ (row >> 3)) << 2]);
        #pragma unroll
        for (int ii = 0; ii < 8; ++ii) {
          acc[ii][jj] += a4[ii].x * b4.x;
          acc[ii][jj] += a4[ii].y * b4.y;
          acc[ii][jj] += a4[ii].z * b4.z;
          acc[ii][jj] += a4[ii].w * b4.w;
        }
      }
    }
    __syncthreads();
  }

  // ---- tree reduce of 8 wave-partials into wave 0 (3 steps, 6 barriers) ----
  if (w >= 4) wr_partial(&P[w - 4][0][0], acc, g, h);
  __syncthreads();
  if (w < 4) rd_accum(&P[w][0][0], acc, g, h);
  __syncthreads();
  if (w == 2) wr_partial(&P[0][0][0], acc, g, h);
  if (w == 3) wr_partial(&P[1][0][0], acc, g, h);
  __syncthreads();
  if (w < 2) rd_accum(&P[w][0][0], acc, g, h);
  __syncthreads();
  if (w == 1) wr_partial(&P[0][0][0], acc, g, h);
  __syncthreads();
  if (w != 0) return;            // wave 0 continues alone; same-wave LDS in-order
  rd_accum(&P[0][0][0], acc, g, h);

  // diag (squared norms) then distances (diag exactly 0)
  if (g == h) {
    #pragma unroll
    for (int ii = 0; ii < 8; ++ii) diag[i0 + ii] = acc[ii][ii];
  }
  #pragma unroll
  for (int ii = 0; ii < 8; ++ii) {
    float di = diag[i0 + ii];
    #pragma unroll
    for (int jj = 0; jj < 8; ++jj) {
      float d2 = di + diag[j0 + jj] - 2.f * acc[ii][jj];
      d2 = fmaxf(d2, 0.f);
      Dw[i0 + ii][j0 + jj] = (d2 > 0.f) ? sqrtf(d2) : 0.f;
    }
  }

  // ---------------- clustering (single wave, lane l owns row l) -------------
  const int l = lane;
  float* Dm = &Dw[0][0];
  int tl = labels[b * NPTS + l];

  // label-equality mask + unique-label count via 8 ballots
  unsigned long long sMask = 0ull;
  int kcnt = 0;
  #pragma unroll
  for (int v = 0; v < 8; ++v) {
    unsigned long long mv = __ballot(tl == v);
    kcnt += (mv != 0ull) ? 1 : 0;
    if (tl == v) sMask = mv;
  }
  int simC = __popcll(sMask);

  // own-row scan: sim/dis sums + row min (strict <: lowest j wins ties)
  float simS = 0.f, disS = 0.f;
  float mval = BIGF; int midx = 0;
  const float* rowp = Dm + l * 65;
  #pragma unroll
  for (int j = 0; j < NPTS; ++j) {
    float v = rowp[j];
    bool sim = (sMask >> j) & 1ull;
    simS += sim ? v : 0.f;
    disS += sim ? 0.f : v;
    bool better = (j != l) && (v < mval);
    mval = better ? v : mval;
    midx = better ? j : midx;
  }
  Dm[l * 65 + l] = BIGF;         // reference inits diagonal to BIG

  unsigned long long actm = ~0ull;
  int cl = l;
  const int merges = NPTS - kcnt;
  #pragma unroll 1
  for (int m = 0; m < merges; ++m) {
    // global argmin over rows' (minval, flat=l*64+midx), lowest-flat tie-break
    bool act = (actm >> l) & 1ull;
    float vf = act ? mval : BIGF;
    int fi = (l << 6) | midx;
    argmin64(vf, fi);            // uniform result in all lanes
    const int a = fi >> 6;       // a < bb by symmetry + lowest-flat
    const int bb = fi & 63;

    // newrow[l] = min(D[l][a], D[l][bb]); update col a and row a
    float va = Dm[l * 65 + a];
    float vb = Dm[l * 65 + bb];
    float nr = fminf(va, vb);
    Dm[l * 65 + a] = nr;
    Dm[a * 65 + l] = nr;

    actm &= ~(1ull << bb);
    cl = (cl == bb) ? a : cl;

    // per-row min maintenance (nr >= mval always; col bb removed, col a -> nr)
    bool actrow = ((actm >> l) & 1ull) && (l != a);
    if (actrow) {
      if (midx == bb) midx = a;
      else if (nr == mval && a < midx) midx = a;
    }
    // fresh rescan for row a: candidates are nr across active lanes != a
    float cv = actrow ? nr : BIGF;
    int cj = l;
    argmin64(cv, cj);
    if (l == a) { mval = cv; midx = cj; }
  }

  // err count via masks: ec = popcount(clusterMask XOR labelMask)
  cls[l] = cl;
  unsigned long long cMask = 0ull;
  const int4* cp = reinterpret_cast<const int4*>(cls);
  #pragma unroll
  for (int jq = 0; jq < 16; ++jq) {
    int4 c4 = cp[jq];
    cMask |= ((unsigned long long)(c4.x == cl)) << (jq * 4 + 0);
    cMask |= ((unsigned long long)(c4.y == cl)) << (jq * 4 + 1);
    cMask |= ((unsigned long long)(c4.z == cl)) << (jq * 4 + 2);
    cMask |= ((unsigned long long)(c4.w == cl)) << (jq * 4 + 3);
  }
  int ec = __popcll(cMask ^ sMask);

  // wave reductions (deterministic butterfly; one-time)
  #pragma unroll
  for (int off = 32; off; off >>= 1) {
    simS += __shfl_xor(simS, off);
    disS += __shfl_xor(disS, off);
    simC += __shfl_xor(simC, off);
    ec   += __shfl_xor(ec, off);
  }
  if (l == 0) {
    simS_o[b] = simS; disS_o[b] = disS;
    simC_o[b] = simC; errC_o[b] = ec;
  }
}

__global__ __launch_bounds__(64) void finalize_kernel(
    const float* __restrict__ simS, const float* __restrict__ disS,
    const int* __restrict__ simC, const int* __restrict__ errC,
    float* __restrict__ out)
{
  const int l = threadIdx.x;
  double ss = 0.0, dd = 0.0, sc = 0.0, ec = 0.0;
  #pragma unroll
  for (int r = 0; r < 4; ++r) {
    int i = (r << 6) + l;        // fixed order -> deterministic
    ss += (double)simS[i];
    dd += (double)disS[i];
    sc += (double)simC[i];
    ec += (double)errC[i];
  }
  #pragma unroll
  for (int off = 32; off; off >>= 1) {
    ss += __shfl_xor(ss, off);
    dd += __shfl_xor(dd, off);
    sc += __shfl_xor(sc, off);
    ec += __shfl_xor(ec, off);
  }
  if (l == 0) {
    const double total = 256.0 * 4096.0;
    double ms = ss / sc;
    double md = dd / (total - sc);
    out[0] = (float)(ec / 256.0 + 0.5 * (ms - md));
  }
}

extern "C" void kernel_launch(void* const* d_in, const int* in_sizes, int n_in,
                              void* d_out, int out_size, void* d_ws, size_t ws_size,
                              hipStream_t stream) {
  const float* q      = (const float*)d_in[0];
  const float* psg    = (const float*)d_in[1];
  const int*   labels = (const int*)d_in[2];
  float* out = (float*)d_out;

  float* simS = (float*)d_ws;          // [256]
  float* disS = simS + 256;            // [256]
  int*   simC = (int*)(disS + 256);    // [256]
  int*   errC = simC + 256;            // [256]

  fused_kernel<<<256, NT, 0, stream>>>(q, psg, labels, simS, disS, simC, errC);
  finalize_kernel<<<1, 64, 0, stream>>>(simS, disS, simC, errC, out);
}